// Round 5
// baseline (73.767 us; speedup 1.0000x reference)
//
#include <hip/hip_runtime.h>
#include <math.h>

#define HID 1024
#define SEQ 4096
#define NB 16
#define CHUNK 64
#define NCHUNK (SEQ / CHUNK)   // 64

typedef float floatx4 __attribute__((ext_vector_type(4)));

// ---------------------------------------------------------------------------
// Kernel A: partial of hp·v_p per (batch, 64-column segment), fp64 accumulation.
// grid (16 batches, 16 jsegs), block 256.
// ---------------------------------------------------------------------------
__global__ __launch_bounds__(256) void kA(const float* __restrict__ tgt,
                                          const float* __restrict__ Wp,
                                          const float* __restrict__ bp,
                                          const float* __restrict__ vp,
                                          double* __restrict__ pPart) {
  __shared__ float tl[HID];
  __shared__ double red[4][64];
  const int b = blockIdx.x;
  const int jseg = blockIdx.y;
  const int j0 = jseg * 64;
  const int tid = threadIdx.x;

  #pragma unroll
  for (int k = 0; k < 4; ++k) tl[tid + k * 256] = tgt[b * HID + tid + k * 256];
  __syncthreads();

  const int jl  = tid & 63;   // column within segment
  const int hp4 = tid >> 6;   // h-quarter 0..3
  double a0 = 0.0, a1 = 0.0, a2 = 0.0, a3 = 0.0;
  const float* wcol = Wp + (size_t)(hp4 * 256) * HID + j0 + jl;
  const float* tq = tl + hp4 * 256;
  for (int i = 0; i < 256; i += 4) {
    a0 += (double)tq[i + 0] * (double)wcol[(size_t)(i + 0) * HID];
    a1 += (double)tq[i + 1] * (double)wcol[(size_t)(i + 1) * HID];
    a2 += (double)tq[i + 2] * (double)wcol[(size_t)(i + 2) * HID];
    a3 += (double)tq[i + 3] * (double)wcol[(size_t)(i + 3) * HID];
  }
  red[hp4][jl] = (a0 + a1) + (a2 + a3);
  __syncthreads();

  if (tid < 64) {
    double s = red[0][tid] + red[1][tid] + red[2][tid] + red[3][tid];
    double hpv = tanh(s + (double)bp[j0 + tid]);
    double val = hpv * (double)vp[j0 + tid];
    #pragma unroll
    for (int off = 32; off; off >>= 1) val += __shfl_xor(val, off);
    if (tid == 0) pPart[b * 16 + jseg] = val;
  }
}

// ---------------------------------------------------------------------------
// Kernel B: fused score+exp+gauss+context partial, single streamed read of src.
// grid 1024 (16 batches x 64 chunks of 64 rows), block 256 (4 waves x 16 rows).
// Gaussian weights hoisted out of the row loop; dot = 4 independent k-partials
// + tree; __expf (e^x fast path) in-loop; tf pre-scaled by 1/sqrt(H).
// ---------------------------------------------------------------------------
__device__ __forceinline__ float4 nt_load4(const float* p) {
  floatx4 v = __builtin_nontemporal_load((const floatx4*)p);
  return make_float4(v.x, v.y, v.z, v.w);
}

__global__ __launch_bounds__(256) void kB(const float* __restrict__ src,
                                          const float* __restrict__ tgt,
                                          const double* __restrict__ pPart,
                                          const float* __restrict__ bv,
                                          float* __restrict__ zPart,
                                          float* __restrict__ ctxPart) {
  const int chunk = blockIdx.x;      // 0..1023
  const int b = chunk >> 6;
  const int c = chunk & 63;
  const int s0 = c * CHUNK;
  const int tid = threadIdx.x;
  const int wave = tid >> 6;
  const int lane = tid & 63;

  // finalize p for this batch (deterministic fp64 sum of 16 partials)
  double lg = (double)bv[0];
  #pragma unroll
  for (int i = 0; i < 16; ++i) lg += pPart[b * 16 + i];
  const float pb = (float)(4096.0 / (1.0 + exp(-lg)));

  const int srow0 = s0 + wave * 16;

  // Gaussian window per row — hoisted off the critical path
  float gr[16];
  #pragma unroll
  for (int r = 0; r < 16; ++r) {
    const float ds = (float)(srow0 + r) - pb;
    gr[r] = __expf(ds * ds * (-1.0f / 2048.0f));
  }

  // target fragment (16 floats per lane), pre-scaled by 1/sqrt(H)
  float4 tf[4];
  const float4* tg4 = (const float4*)(tgt + b * HID);
  #pragma unroll
  for (int k = 0; k < 4; ++k) {
    tf[k] = tg4[k * 64 + lane];
    tf[k].x *= 0.03125f; tf[k].y *= 0.03125f;
    tf[k].z *= 0.03125f; tf[k].w *= 0.03125f;
  }

  float4 acc[4];
  #pragma unroll
  for (int k = 0; k < 4; ++k) acc[k] = make_float4(0.f, 0.f, 0.f, 0.f);
  float z = 0.f;

  const float* base = src + ((size_t)b * SEQ + srow0) * HID;

  float4 x[2][4];
  #pragma unroll
  for (int k = 0; k < 4; ++k) x[0][k] = nt_load4(base + (k * 64 + lane) * 4);

  #pragma unroll
  for (int r = 0; r < 16; ++r) {
    const int cur = r & 1, nxt = cur ^ 1;
    if (r + 1 < 16) {
      #pragma unroll
      for (int k = 0; k < 4; ++k)
        x[nxt][k] = nt_load4(base + ((r + 1) * 256 + k * 64 + lane) * 4);
    }

    // 4 independent partial dots, then a depth-2 tree
    float d[4];
    #pragma unroll
    for (int k = 0; k < 4; ++k) {
      float t0 = x[cur][k].x * tf[k].x;
      t0 = fmaf(x[cur][k].y, tf[k].y, t0);
      t0 = fmaf(x[cur][k].z, tf[k].z, t0);
      t0 = fmaf(x[cur][k].w, tf[k].w, t0);
      d[k] = t0;
    }
    float dot = (d[0] + d[1]) + (d[2] + d[3]);
    #pragma unroll
    for (int off = 32; off; off >>= 1) dot += __shfl_xor(dot, off);

    const float w = __expf(dot);            // dot = score/sqrt(H) already
    z += w;
    const float wg = w * gr[r];
    #pragma unroll
    for (int k = 0; k < 4; ++k) {
      acc[k].x = fmaf(wg, x[cur][k].x, acc[k].x);
      acc[k].y = fmaf(wg, x[cur][k].y, acc[k].y);
      acc[k].z = fmaf(wg, x[cur][k].z, acc[k].z);
      acc[k].w = fmaf(wg, x[cur][k].w, acc[k].w);
    }
  }

  // combine 4 waves via LDS
  __shared__ float lctx[4][HID];
  __shared__ float lz[4];
  #pragma unroll
  for (int k = 0; k < 4; ++k)
    *(float4*)&lctx[wave][k * 256 + lane * 4] = acc[k];
  if (lane == 0) lz[wave] = z;
  __syncthreads();

  float4 s4 = make_float4(0.f, 0.f, 0.f, 0.f);
  #pragma unroll
  for (int w2 = 0; w2 < 4; ++w2) {
    float4 v = *(const float4*)&lctx[w2][tid * 4];
    s4.x += v.x; s4.y += v.y; s4.z += v.z; s4.w += v.w;
  }
  ((float4*)ctxPart)[(size_t)chunk * 256 + tid] = s4;
  if (tid == 0) zPart[chunk] = lz[0] + lz[1] + lz[2] + lz[3];
}

// ---------------------------------------------------------------------------
// Kernel C: combine chunk partials, divide by Z.
// grid (16 batches, 16 hsegs of 64 cols), block 256 (4 chunk-groups x 64 cols).
// ---------------------------------------------------------------------------
__global__ __launch_bounds__(256) void kC(const float* __restrict__ zPart,
                                          const float* __restrict__ ctxPart,
                                          float* __restrict__ out) {
  __shared__ float red[4][64];
  const int b = blockIdx.x;
  const int hseg = blockIdx.y;
  const int tid = threadIdx.x;
  const int col = tid & 63;
  const int grp = tid >> 6;

  float acc = 0.f;
  #pragma unroll
  for (int i = 0; i < 16; ++i) {
    const int chunk = grp * 16 + i;
    acc += ctxPart[((size_t)(b * NCHUNK + chunk)) * HID + hseg * 64 + col];
  }
  red[grp][col] = acc;
  __syncthreads();

  if (tid < 64) {
    float Z = 0.f;
    for (int c = 0; c < NCHUNK; ++c) Z += zPart[b * NCHUNK + c];
    const float s = red[0][tid] + red[1][tid] + red[2][tid] + red[3][tid];
    out[b * HID + hseg * 64 + tid] = s / Z;
  }
}

// ---------------------------------------------------------------------------
extern "C" void kernel_launch(void* const* d_in, const int* in_sizes, int n_in,
                              void* d_out, int out_size, void* d_ws, size_t ws_size,
                              hipStream_t stream) {
  const float* src = (const float*)d_in[0];   // (16, 4096, 1024)
  const float* tgt = (const float*)d_in[1];   // (16, 1024)
  const float* Wp  = (const float*)d_in[2];   // (1024, 1024)
  const float* bp  = (const float*)d_in[3];   // (1024,)
  const float* vp  = (const float*)d_in[4];   // (1024,)
  const float* bv  = (const float*)d_in[5];   // scalar
  float* out = (float*)d_out;

  double* pPart  = (double*)d_ws;                          // 256 doubles
  float* zPart   = (float*)((char*)d_ws + 4096);           // 1024 floats
  float* ctxPart = (float*)((char*)d_ws + 8192);           // 4 MB

  kA<<<dim3(NB, 16), 256, 0, stream>>>(tgt, Wp, bp, vp, pPart);
  kB<<<NB * NCHUNK, 256, 0, stream>>>(src, tgt, pPart, bv, zPart, ctxPart);
  kC<<<dim3(NB, 16), 256, 0, stream>>>(zPart, ctxPart, out);
}